// Round 9
// baseline (1500.304 us; speedup 1.0000x reference)
//
#include <hip/hip_runtime.h>

#define HID 128
#define SB 1024
#define LDA 136   // bf16 plane row stride (shorts); 272B rows, 16B-aligned

// Harness contract: integer inputs arrive as int32 (int64 cast = R3 core dump).
// R6: no big per-lane arrays (w[128] spilled -> 325MB spill stores).
// R7: VALU GEMM is LDS-BW-bound; bf16-split MFMA is the right core.
// R8: agg round-trip + same-address f64 atomics were the GEMM overhead ->
//     fuse gather into GEMM1, per-block BN partials + separate reduce.

__device__ __forceinline__ unsigned short bf16h(float x) {
    unsigned int u = __float_as_uint(x);
    return (unsigned short)((u + 0x7fffu + ((u >> 16) & 1u)) >> 16);  // RNE
}
__device__ __forceinline__ float bf16f(unsigned short h) {
    return __uint_as_float(((unsigned int)h) << 16);
}

using bfrag = __attribute__((ext_vector_type(8))) short;   // 8 bf16 = 4 VGPR
using f32x4v = __attribute__((ext_vector_type(4))) float;  // C/D frag

// ---------------- CSR build ----------------
__global__ void k_hist(const int* __restrict__ dst, int* __restrict__ deg, int e) {
    int i = blockIdx.x * blockDim.x + threadIdx.x;
    if (i < e) atomicAdd(&deg[dst[i]], 1);
}

__global__ __launch_bounds__(SB)
void k_scan1(const int* __restrict__ deg, int* __restrict__ rs,
             int* __restrict__ partials, int n) {
    __shared__ int sh[SB];
    int t = threadIdx.x;
    int i = blockIdx.x * SB + t;
    int v = (i < n) ? deg[i] : 0;
    sh[t] = v;
    __syncthreads();
    for (int off = 1; off < SB; off <<= 1) {
        int add = (t >= off) ? sh[t - off] : 0;
        __syncthreads();
        sh[t] += add;
        __syncthreads();
    }
    if (i < n) rs[i] = sh[t] - v;
    if (t == SB - 1) partials[blockIdx.x] = sh[t];
}

__global__ __launch_bounds__(256)
void k_scan2(int* __restrict__ partials, int* __restrict__ rs, int nb, int n) {
    __shared__ int sh[256];
    int t = threadIdx.x;
    int v = (t < nb) ? partials[t] : 0;
    sh[t] = v;
    __syncthreads();
    for (int off = 1; off < 256; off <<= 1) {
        int add = (t >= off) ? sh[t - off] : 0;
        __syncthreads();
        sh[t] += add;
        __syncthreads();
    }
    if (t < nb) partials[t] = sh[t] - v;
    if (t == 255) rs[n] = sh[t];
}

__global__ __launch_bounds__(SB)
void k_scan3(int* __restrict__ rs, int* __restrict__ cur,
             const int* __restrict__ partials, int n) {
    int i = blockIdx.x * SB + threadIdx.x;
    if (i < n) {
        int v = rs[i] + partials[blockIdx.x];
        rs[i] = v;
        cur[i] = v;
    }
}

// XCD-windowed scatter (R5 fix for partial-line write amplification)
__global__ __launch_bounds__(256)
void k_scatter(const int* __restrict__ src, const int* __restrict__ dst,
               int* __restrict__ cur, int* __restrict__ csr, int e, int nwin) {
    int p = blockIdx.x & 7;
    int slot = blockIdx.x >> 3;
    int nslots = gridDim.x >> 3;
    int lo = p * nwin, hi = lo + nwin;
    int stride = nslots * blockDim.x;
    for (int i = slot * blockDim.x + threadIdx.x; i < e; i += stride) {
        int d = dst[i];
        if (d >= lo && d < hi) {
            int pos = atomicAdd(&cur[d], 1);
            csr[pos] = src[i];
        }
    }
}

// ---------------- W pre-pack: per-fragment bf16 hi/lo planes ----------------
__global__ __launch_bounds__(256)
void k_wpack(const float* __restrict__ W1, const float* __restrict__ W2,
             short* __restrict__ wph, short* __restrict__ wpl) {
    int m = blockIdx.x >> 3;
    int part = blockIdx.x & 7;
    const float* src = (m < 4) ? (W1 + (size_t)m * 16384) : (W2 + (size_t)(m - 4) * 16384);
    for (int i = 0; i < 8; ++i) {
        int e = part * 2048 + threadIdx.x + 256 * i;
        int j = e & 7, g = (e >> 3) & 3, c = (e >> 5) & 127, kc = e >> 12;
        int k = kc * 32 + g * 8 + j;
        float v = src[k * 128 + c];
        unsigned short h = bf16h(v);
        unsigned short l = bf16h(v - bf16f(h));
        wph[(size_t)m * 16384 + e] = (short)h;
        wpl[(size_t)m * 16384 + e] = (short)l;
    }
}

// ---------------- fused layer-front: gather + bf16-split + MFMA GEMM1 ----------------
// Block = 64 dst rows; wave w gathers rows [w*16, w*16+16) (lane = float2 slice),
// writes bf16 hi/lo planes to LDS, then the R8 MFMA core computes A@W1+b1 -> out.
// BN partials per block -> psum/psq[block][128] (NO atomics).
__global__ __launch_bounds__(256, 4)
void k_layer1(const float* __restrict__ x, const int* __restrict__ rs,
              const int* __restrict__ csr,
              const short* __restrict__ WBh, const short* __restrict__ WBl,
              const float* __restrict__ bias, float* __restrict__ out,
              double* __restrict__ psum, double* __restrict__ psq, int nrows) {
    __shared__ __align__(16) short Ah[64 * LDA];
    __shared__ __align__(16) short Al[64 * LDA];
    int t = threadIdx.x;
    int w = t >> 6, lane = t & 63;
    int row0 = blockIdx.x * 64;
    int nr = min(64, nrows - row0);
    const float2* xp = reinterpret_cast<const float2*>(x);

    // ---- gather + split ----
    for (int rr = 0; rr < 16; ++rr) {
        int rl = w * 16 + rr;
        int row = row0 + rl;
        float2 acc = make_float2(0.f, 0.f);
        if (row < nrows) {
            acc = xp[(size_t)row * 64 + lane];
            int beg = rs[row], end = rs[row + 1];
            int j = beg;
            for (; j + 8 <= end; j += 8) {
                int s0 = csr[j], s1 = csr[j + 1], s2 = csr[j + 2], s3 = csr[j + 3];
                int s4 = csr[j + 4], s5 = csr[j + 5], s6 = csr[j + 6], s7 = csr[j + 7];
                float2 v0 = xp[(size_t)s0 * 64 + lane];
                float2 v1 = xp[(size_t)s1 * 64 + lane];
                float2 v2 = xp[(size_t)s2 * 64 + lane];
                float2 v3 = xp[(size_t)s3 * 64 + lane];
                float2 v4 = xp[(size_t)s4 * 64 + lane];
                float2 v5 = xp[(size_t)s5 * 64 + lane];
                float2 v6 = xp[(size_t)s6 * 64 + lane];
                float2 v7 = xp[(size_t)s7 * 64 + lane];
                acc.x += ((v0.x + v1.x) + (v2.x + v3.x)) + ((v4.x + v5.x) + (v6.x + v7.x));
                acc.y += ((v0.y + v1.y) + (v2.y + v3.y)) + ((v4.y + v5.y) + (v6.y + v7.y));
            }
            for (; j < end; ++j) {
                int s = csr[j];
                float2 v = xp[(size_t)s * 64 + lane];
                acc.x += v.x;
                acc.y += v.y;
            }
        }
        unsigned short hx = bf16h(acc.x), hy = bf16h(acc.y);
        short2 hv = make_short2((short)hx, (short)hy);
        short2 lv = make_short2((short)bf16h(acc.x - bf16f(hx)),
                                (short)bf16h(acc.y - bf16f(hy)));
        *reinterpret_cast<short2*>(&Ah[rl * LDA + lane * 2]) = hv;  // consecutive banks
        *reinterpret_cast<short2*>(&Al[rl * LDA + lane * 2]) = lv;
    }
    __syncthreads();

    // ---- MFMA core (R8-verified layout) ----
    int arow = lane & 15, ag = lane >> 4;
    const bfrag* WH = reinterpret_cast<const bfrag*>(WBh);
    const bfrag* WL = reinterpret_cast<const bfrag*>(WBl);
    f32x4v acc[8];
#pragma unroll
    for (int ct = 0; ct < 8; ++ct) acc[ct] = (f32x4v){0.f, 0.f, 0.f, 0.f};
#pragma unroll
    for (int kc = 0; kc < 4; ++kc) {
        int aoff = (w * 16 + arow) * LDA + kc * 32 + ag * 8;
        bfrag ah = *reinterpret_cast<const bfrag*>(&Ah[aoff]);
        bfrag al = *reinterpret_cast<const bfrag*>(&Al[aoff]);
#pragma unroll
        for (int ct = 0; ct < 8; ++ct) {
            int widx = (kc * 128 + ct * 16 + arow) * 4 + ag;
            bfrag bh = WH[widx];
            bfrag bl = WL[widx];
            acc[ct] = __builtin_amdgcn_mfma_f32_16x16x32_bf16(ah, bh, acc[ct], 0, 0, 0);
            acc[ct] = __builtin_amdgcn_mfma_f32_16x16x32_bf16(ah, bl, acc[ct], 0, 0, 0);
            acc[ct] = __builtin_amdgcn_mfma_f32_16x16x32_bf16(al, bh, acc[ct], 0, 0, 0);
        }
    }

    // ---- epilogue: bias, store, BN partials (block-local, no atomics) ----
    double s0[8], s1[8];
#pragma unroll
    for (int ct = 0; ct < 8; ++ct) {
        int c = ct * 16 + arow;
        float bv = bias[c];
        double a0 = 0.0, a1 = 0.0;
#pragma unroll
        for (int reg = 0; reg < 4; ++reg) {
            int rl = w * 16 + ag * 4 + reg;
            if (rl < nr) {
                size_t r = (size_t)(row0 + rl);
                float v = acc[ct][reg] + bv;
                out[r * HID + c] = v;
                double vd = (double)v;
                a0 += vd;
                a1 = fma(vd, vd, a1);
            }
        }
        s0[ct] = a0;
        s1[ct] = a1;
    }
    __syncthreads();  // done reading Ah/Al
    double* rsum = reinterpret_cast<double*>(Ah);  // [4 waves][128 cols]
    double* rsq  = reinterpret_cast<double*>(Al);
#pragma unroll
    for (int ct = 0; ct < 8; ++ct) {
        double a0 = s0[ct], a1 = s1[ct];
        a0 += __shfl_xor(a0, 16);
        a0 += __shfl_xor(a0, 32);
        a1 += __shfl_xor(a1, 16);
        a1 += __shfl_xor(a1, 32);
        if (lane < 16) {
            rsum[w * 128 + ct * 16 + lane] = a0;
            rsq[w * 128 + ct * 16 + lane] = a1;
        }
    }
    __syncthreads();
    if (t < 128) {
        double a = (rsum[t] + rsum[128 + t]) + (rsum[256 + t] + rsum[384 + t]);
        double b = (rsq[t] + rsq[128 + t]) + (rsq[256 + t] + rsq[384 + t]);
        psum[(size_t)blockIdx.x * HID + t] = a;
        psq[(size_t)blockIdx.x * HID + t] = b;
    }
}

// ---------------- bf16-split MFMA GEMM2: out = relu(A@W+b) + xres; BN+ReLU on load ----
__global__ __launch_bounds__(256, 4)
void k_gemm2(const float* __restrict__ A, const short* __restrict__ WBh,
             const short* __restrict__ WBl, const float* __restrict__ bias,
             float* __restrict__ out, const float* __restrict__ xres,
             const float* __restrict__ bn_scale, const float* __restrict__ bn_shift,
             int nrows) {
    __shared__ __align__(16) short Ah[64 * LDA];
    __shared__ __align__(16) short Al[64 * LDA];
    int t = threadIdx.x;
    int w = t >> 6, lane = t & 63;
    int row0 = blockIdx.x * 64;
    int nr = min(64, nrows - row0);

    {
        const float4* sc4 = reinterpret_cast<const float4*>(bn_scale);
        const float4* sh4 = reinterpret_cast<const float4*>(bn_shift);
#pragma unroll
        for (int i = 0; i < 8; ++i) {
            int idx = t + 256 * i;
            int row = idx >> 5;
            int c4 = (idx & 31) * 4;
            float4 v = make_float4(0.f, 0.f, 0.f, 0.f);
            if (row < nr) {
                v = *reinterpret_cast<const float4*>(A + (size_t)(row0 + row) * HID + c4);
                float4 a = sc4[idx & 31], bb = sh4[idx & 31];
                v.x = fmaxf(fmaf(v.x, a.x, bb.x), 0.f);
                v.y = fmaxf(fmaf(v.y, a.y, bb.y), 0.f);
                v.z = fmaxf(fmaf(v.z, a.z, bb.z), 0.f);
                v.w = fmaxf(fmaf(v.w, a.w, bb.w), 0.f);
            }
            unsigned short h0 = bf16h(v.x), h1 = bf16h(v.y), h2 = bf16h(v.z), h3 = bf16h(v.w);
            short4 hv = make_short4((short)h0, (short)h1, (short)h2, (short)h3);
            short4 lv = make_short4((short)bf16h(v.x - bf16f(h0)), (short)bf16h(v.y - bf16f(h1)),
                                    (short)bf16h(v.z - bf16f(h2)), (short)bf16h(v.w - bf16f(h3)));
            *reinterpret_cast<short4*>(&Ah[row * LDA + c4]) = hv;
            *reinterpret_cast<short4*>(&Al[row * LDA + c4]) = lv;
        }
    }
    __syncthreads();

    int arow = lane & 15, ag = lane >> 4;
    const bfrag* WH = reinterpret_cast<const bfrag*>(WBh);
    const bfrag* WL = reinterpret_cast<const bfrag*>(WBl);
    f32x4v acc[8];
#pragma unroll
    for (int ct = 0; ct < 8; ++ct) acc[ct] = (f32x4v){0.f, 0.f, 0.f, 0.f};
#pragma unroll
    for (int kc = 0; kc < 4; ++kc) {
        int aoff = (w * 16 + arow) * LDA + kc * 32 + ag * 8;
        bfrag ah = *reinterpret_cast<const bfrag*>(&Ah[aoff]);
        bfrag al = *reinterpret_cast<const bfrag*>(&Al[aoff]);
#pragma unroll
        for (int ct = 0; ct < 8; ++ct) {
            int widx = (kc * 128 + ct * 16 + arow) * 4 + ag;
            bfrag bh = WH[widx];
            bfrag bl = WL[widx];
            acc[ct] = __builtin_amdgcn_mfma_f32_16x16x32_bf16(ah, bh, acc[ct], 0, 0, 0);
            acc[ct] = __builtin_amdgcn_mfma_f32_16x16x32_bf16(ah, bl, acc[ct], 0, 0, 0);
            acc[ct] = __builtin_amdgcn_mfma_f32_16x16x32_bf16(al, bh, acc[ct], 0, 0, 0);
        }
    }
#pragma unroll
    for (int ct = 0; ct < 8; ++ct) {
        int c = ct * 16 + arow;
        float bv = bias[c];
#pragma unroll
        for (int reg = 0; reg < 4; ++reg) {
            int rl = w * 16 + ag * 4 + reg;
            if (rl < nr) {
                size_t r = (size_t)(row0 + rl);
                float v = fmaxf(acc[ct][reg] + bv, 0.f) + xres[r * HID + c];
                out[r * HID + c] = v;
            }
        }
    }
}

// ---------------- BN partial reduce + finalize (one block) ----------------
__global__ __launch_bounds__(1024)
void k_bnfinal2(const double* __restrict__ psum, const double* __restrict__ psq,
                const float* __restrict__ gamma, const float* __restrict__ beta,
                float* __restrict__ scale, float* __restrict__ shift,
                int nb, double inv_n) {
    __shared__ double ls[8 * 128];
    __shared__ double lq[8 * 128];
    int t = threadIdx.x;
    int col = t & 127, part = t >> 7;
    double a = 0.0, b = 0.0;
    for (int bi = part; bi < nb; bi += 8) {
        a += psum[(size_t)bi * 128 + col];
        b += psq[(size_t)bi * 128 + col];
    }
    ls[t] = a;
    lq[t] = b;
    __syncthreads();
    if (t < 128) {
        double sa = 0.0, sb = 0.0;
#pragma unroll
        for (int p = 0; p < 8; ++p) {
            sa += ls[p * 128 + t];
            sb += lq[p * 128 + t];
        }
        double m = sa * inv_n;
        double var = sb * inv_n - m * m;
        float sc = gamma[t] * rsqrtf((float)var + 1e-5f);
        scale[t] = sc;
        shift[t] = beta[t] - (float)m * sc;
    }
}

// ---------------- global_add_pool over sorted batch (int32) ----------------
__global__ void k_pool(const float* __restrict__ xf, const int* __restrict__ batch,
                       float* __restrict__ pooled, int n) {
    int g = blockIdx.x;
    int lo = 0, hi = n;
    while (lo < hi) { int mid = (lo + hi) >> 1; if (batch[mid] < g) lo = mid + 1; else hi = mid; }
    int beg = lo;
    lo = 0; hi = n;
    int g1 = g + 1;
    while (lo < hi) { int mid = (lo + hi) >> 1; if (batch[mid] < g1) lo = mid + 1; else hi = mid; }
    int end = lo;
    int t = threadIdx.x;
    float a0 = 0.f, a1 = 0.f, a2 = 0.f, a3 = 0.f;
    int r = beg;
    for (; r + 4 <= end; r += 4) {
        a0 += xf[(size_t)(r + 0) * HID + t];
        a1 += xf[(size_t)(r + 1) * HID + t];
        a2 += xf[(size_t)(r + 2) * HID + t];
        a3 += xf[(size_t)(r + 3) * HID + t];
    }
    for (; r < end; ++r) a0 += xf[(size_t)r * HID + t];
    pooled[(size_t)blockIdx.x * HID + t] = (a0 + a1) + (a2 + a3);
}

extern "C" void kernel_launch(void* const* d_in, const int* in_sizes, int n_in,
                              void* d_out, int out_size, void* d_ws, size_t ws_size,
                              hipStream_t stream) {
    const float* x      = (const float*)d_in[0];
    const int* ei       = (const int*)d_in[1];
    const int* batch    = (const int*)d_in[2];
    const float* W1     = (const float*)d_in[3];
    const float* b1     = (const float*)d_in[4];
    const float* gamma  = (const float*)d_in[5];
    const float* beta   = (const float*)d_in[6];
    const float* W2     = (const float*)d_in[7];
    const float* b2     = (const float*)d_in[8];

    const int N = in_sizes[0] / HID;
    const int E = in_sizes[1] / 2;
    const int L = in_sizes[3] / (HID * HID);
    const int G = (out_size - N * HID) / HID;

    const int* esrc = ei;
    const int* edst = ei + E;

    char* ws = (char*)d_ws;
    size_t off = 0;
    auto alloc = [&](size_t bytes) {
        void* p = ws + off;
        off += (bytes + 255) & ~(size_t)255;
        return p;
    };
    const int GB = (N + 63) / 64;  // GEMM/layer blocks
    float* bufA = (float*)alloc((size_t)N * HID * 4);
    float* bufh = (float*)alloc((size_t)N * HID * 4);
    int* deg = (int*)alloc((size_t)N * 4);
    int* rs  = (int*)alloc(((size_t)N + 1) * 4);
    int* cur = (int*)alloc((size_t)N * 4);
    int* csr = (int*)alloc((size_t)E * 4);
    int* partials   = (int*)alloc(256 * 4);
    double* psum    = (double*)alloc((size_t)GB * HID * 8);
    double* psq     = (double*)alloc((size_t)GB * HID * 8);
    float* bn_scale = (float*)alloc(HID * 4);
    float* bn_shift = (float*)alloc(HID * 4);
    short* wph = (short*)alloc((size_t)8 * 16384 * 2);
    short* wpl = (short*)alloc((size_t)8 * 16384 * 2);
    (void)ws_size;  // ~114MB

    float* xout   = (float*)d_out;
    float* pooled = (float*)d_out + (size_t)N * HID;
    float* bufB   = xout;  // d_out node region doubles as ping-pong scratch

    const int NB = (N + SB - 1) / SB;
    const int NWIN = (N + 7) / 8;

    hipMemsetAsync(deg, 0, (size_t)N * 4, stream);
    k_wpack<<<64, 256, 0, stream>>>(W1, W2, wph, wpl);
    k_hist<<<(E + 255) / 256, 256, 0, stream>>>(edst, deg, E);
    k_scan1<<<NB, SB, 0, stream>>>(deg, rs, partials, N);
    k_scan2<<<1, 256, 0, stream>>>(partials, rs, NB, N);
    k_scan3<<<NB, SB, 0, stream>>>(rs, cur, partials, N);
    k_scatter<<<2048, 256, 0, stream>>>(esrc, edst, cur, csr, E, NWIN);

    // Layer schedule: l0: x->bufA; l1: bufA->bufB(d_out); l2: bufB->bufA; l3: bufA->xout
    const float* xl = x;
    for (int l = 0; l < L; ++l) {
        float* outb = (l == L - 1) ? xout : ((l & 1) ? bufB : bufA);
        const short* w1h = wph + (size_t)l * 16384;
        const short* w1l = wpl + (size_t)l * 16384;
        const short* w2h = wph + (size_t)(l + 4) * 16384;
        const short* w2l = wpl + (size_t)(l + 4) * 16384;

        k_layer1<<<GB, 256, 0, stream>>>(xl, rs, csr, w1h, w1l,
                                         b1 + (size_t)l * HID, bufh, psum, psq, N);
        k_bnfinal2<<<1, 1024, 0, stream>>>(psum, psq, gamma + (size_t)l * HID,
                                           beta + (size_t)l * HID, bn_scale, bn_shift,
                                           GB, 1.0 / (double)N);
        k_gemm2<<<GB, 256, 0, stream>>>(bufh, w2h, w2l, b2 + (size_t)l * HID, outb,
                                        xl, bn_scale, bn_shift, N);
        xl = outb;
    }

    k_pool<<<G, HID, 0, stream>>>(xout, batch, pooled, N);
}